// Round 1
// baseline (697.759 us; speedup 1.0000x reference)
//
#include <hip/hip_runtime.h>
#include <math.h>

#define NT   16384
#define KD   2048
#define PROJ 256
#define NH   4
#define HD   64
#define NE   64

#define GATES_OFF 0
#define IDX_OFF   (NT * NE)            // 1048576
#define GL_OFF    (NT * NE + NT * 2)   // 1081344

// ---------------------------------------------------------------------------
// K1: h = x @ Wp + bp   (16384x2048 * 2048x256)
// Block tile: 128m x 64n, BK=16. 256 threads = 4 waves; each wave: 32m x 64n.
// lane = n (coalesced B reads + C stores); A fragments via LDS broadcast.
// Chunk-folded f32 accumulation (every 8 k-tiles) to reduce rounding noise.
// ---------------------------------------------------------------------------
#define K1_BM 128
#define K1_BN 64
#define K1_BK 16

__global__ __launch_bounds__(256) void k1_gemm(const float* __restrict__ x,
                                               const float* __restrict__ Wp,
                                               const float* __restrict__ bp,
                                               float* __restrict__ h)
{
    __shared__ float As[K1_BK][K1_BM];   // 8 KB, k-major
    __shared__ float Bs[K1_BK][K1_BN];   // 4 KB

    const int t    = threadIdx.x;
    const int lane = t & 63;
    const int wid  = t >> 6;
    const int m0   = blockIdx.x * K1_BM;
    const int n0   = blockIdx.y * K1_BN;
    const int wm0  = wid * 32;

    float acc[32], accT[32];
#pragma unroll
    for (int i = 0; i < 32; ++i) { acc[i] = 0.f; accT[i] = 0.f; }

    // staging-load index decomposition
    const int ami = t >> 2;          // 0..63 (and +64 for second half)
    const int akq = (t & 3) * 4;     // k sub-offset 0,4,8,12
    const int bkr = t >> 4;          // 0..15
    const int bnq = (t & 15) * 4;    // 0..60

    const float* xa0 = &x[(size_t)(m0 + ami) * KD + akq];
    const float* xa1 = &x[(size_t)(m0 + ami + 64) * KD + akq];
    const float* wb  = &Wp[(size_t)bkr * PROJ + n0 + bnq];

    float4 pa0 = *(const float4*)(xa0);
    float4 pa1 = *(const float4*)(xa1);
    float4 pb  = *(const float4*)(wb);

    for (int ti = 0; ti < KD / K1_BK; ++ti) {
        const int k0 = ti * K1_BK;
        __syncthreads();                     // previous tile fully consumed
        As[akq + 0][ami] = pa0.x; As[akq + 1][ami] = pa0.y;
        As[akq + 2][ami] = pa0.z; As[akq + 3][ami] = pa0.w;
        As[akq + 0][ami + 64] = pa1.x; As[akq + 1][ami + 64] = pa1.y;
        As[akq + 2][ami + 64] = pa1.z; As[akq + 3][ami + 64] = pa1.w;
        *(float4*)&Bs[bkr][bnq] = pb;
        __syncthreads();
        if (k0 + K1_BK < KD) {               // prefetch next tile into regs
            pa0 = *(const float4*)(xa0 + k0 + K1_BK);
            pa1 = *(const float4*)(xa1 + k0 + K1_BK);
            pb  = *(const float4*)(wb + (size_t)(k0 + K1_BK) * PROJ);
        }
#pragma unroll
        for (int kk = 0; kk < K1_BK; ++kk) {
            const float b = Bs[kk][lane];    // coalesced, 2 lanes/bank (free)
#pragma unroll
            for (int jq = 0; jq < 8; ++jq) { // broadcast b128 reads of A
                const float4 a = *(const float4*)&As[kk][wm0 + jq * 4];
                acc[jq * 4 + 0] = fmaf(a.x, b, acc[jq * 4 + 0]);
                acc[jq * 4 + 1] = fmaf(a.y, b, acc[jq * 4 + 1]);
                acc[jq * 4 + 2] = fmaf(a.z, b, acc[jq * 4 + 2]);
                acc[jq * 4 + 3] = fmaf(a.w, b, acc[jq * 4 + 3]);
            }
        }
        if ((ti & 7) == 7) {                 // fold every 128 k: cuts acc noise
#pragma unroll
            for (int i = 0; i < 32; ++i) { accT[i] += acc[i]; acc[i] = 0.f; }
        }
    }

    const float bpv = bp[n0 + lane];
#pragma unroll
    for (int i = 0; i < 32; ++i) {
        h[(size_t)(m0 + wm0 + i) * PROJ + n0 + lane] = accT[i] + bpv;
    }
}

// ---------------------------------------------------------------------------
// K2: per head  hl[:,h*64+e] = relu(h[:,h,:] @ W1[h] + b1[h]) @ W2[h] + b2[h]
// Block: 256 thr = 4 waves, 64 tokens/block, head = blockIdx.y.
// W1[h], W2[h] staged in LDS ([d][e]); 4 tokens register-blocked per wave.
// ---------------------------------------------------------------------------
__global__ __launch_bounds__(256) void k2_heads(const float* __restrict__ h,
                                                const float* __restrict__ W1,
                                                const float* __restrict__ b1,
                                                const float* __restrict__ W2,
                                                const float* __restrict__ b2,
                                                float* __restrict__ hl)
{
    __shared__ float W1s[HD][HD];        // 16 KB  [d][e]
    __shared__ float W2s[HD][HD];        // 16 KB
    __shared__ float hbuf[4][4][HD];     // 4 KB   [wave][c][d]
    __shared__ float hidbuf[4][4][HD];   // 4 KB

    const int t    = threadIdx.x;
    const int lane = t & 63;
    const int w    = t >> 6;
    const int head = blockIdx.y;
    const int t0   = blockIdx.x * 64;

    {   // stage weights: 1024 float4 each
        const float4* g1 = (const float4*)(W1 + (size_t)head * HD * HD);
        const float4* g2 = (const float4*)(W2 + (size_t)head * HD * HD);
        float4* s1 = (float4*)&W1s[0][0];
        float4* s2 = (float4*)&W2s[0][0];
#pragma unroll
        for (int q = 0; q < 4; ++q) {
            s1[t + q * 256] = g1[t + q * 256];
            s2[t + q * 256] = g2[t + q * 256];
        }
    }
    const float b1v = b1[head * HD + lane];
    const float b2v = b2[head * HD + lane];
    __syncthreads();

    for (int r = 0; r < 4; ++r) {
        const int tk0 = t0 + w * 16 + r * 4;
#pragma unroll
        for (int c = 0; c < 4; ++c)
            hbuf[w][c][lane] = h[(size_t)(tk0 + c) * PROJ + head * HD + lane];
        __syncthreads();

        float acc[4] = { b1v, b1v, b1v, b1v };
#pragma unroll
        for (int d4 = 0; d4 < HD; d4 += 4) {
            const float4 hb0 = *(const float4*)&hbuf[w][0][d4];
            const float4 hb1 = *(const float4*)&hbuf[w][1][d4];
            const float4 hb2 = *(const float4*)&hbuf[w][2][d4];
            const float4 hb3 = *(const float4*)&hbuf[w][3][d4];
#pragma unroll
            for (int dd = 0; dd < 4; ++dd) {
                const float wv = W1s[d4 + dd][lane];
                acc[0] = fmaf(((const float*)&hb0)[dd], wv, acc[0]);
                acc[1] = fmaf(((const float*)&hb1)[dd], wv, acc[1]);
                acc[2] = fmaf(((const float*)&hb2)[dd], wv, acc[2]);
                acc[3] = fmaf(((const float*)&hb3)[dd], wv, acc[3]);
            }
        }
#pragma unroll
        for (int c = 0; c < 4; ++c)
            hidbuf[w][c][lane] = fmaxf(acc[c], 0.f);
        __syncthreads();

        float acc2[4] = { b2v, b2v, b2v, b2v };
#pragma unroll
        for (int d4 = 0; d4 < HD; d4 += 4) {
            const float4 hb0 = *(const float4*)&hidbuf[w][0][d4];
            const float4 hb1 = *(const float4*)&hidbuf[w][1][d4];
            const float4 hb2 = *(const float4*)&hidbuf[w][2][d4];
            const float4 hb3 = *(const float4*)&hidbuf[w][3][d4];
#pragma unroll
            for (int dd = 0; dd < 4; ++dd) {
                const float wv = W2s[d4 + dd][lane];
                acc2[0] = fmaf(((const float*)&hb0)[dd], wv, acc2[0]);
                acc2[1] = fmaf(((const float*)&hb1)[dd], wv, acc2[1]);
                acc2[2] = fmaf(((const float*)&hb2)[dd], wv, acc2[2]);
                acc2[3] = fmaf(((const float*)&hb3)[dd], wv, acc2[3]);
            }
        }
#pragma unroll
        for (int c = 0; c < 4; ++c)
            hl[(size_t)(tk0 + c) * PROJ + head * HD + lane] = acc2[c];
        __syncthreads();   // protect hbuf/hidbuf before next round
    }
}

// ---------------------------------------------------------------------------
// K3: gate_logits = hl @ Wc + bc, /clip(T), top-2 + softmax, scatter outputs.
// Block: 256 thr = 4 waves, 32 tokens/block; Wc staged in LDS (64 KB).
// lane = expert e. top_idx written as float (flat f32 output buffer).
// ---------------------------------------------------------------------------
__global__ __launch_bounds__(256) void k3_gate(const float* __restrict__ hl,
                                               const float* __restrict__ Wc,
                                               const float* __restrict__ bc,
                                               const float* __restrict__ temp,
                                               float* __restrict__ out)
{
    __shared__ float Wcs[PROJ][NE];      // 64 KB  [j][e]
    __shared__ float hlb[4][4][PROJ];    // 16 KB  [wave][c][j]

    const int t    = threadIdx.x;
    const int lane = t & 63;
    const int w    = t >> 6;
    const int t0   = blockIdx.x * 32;

    {   // stage Wc: 4096 float4
        const float4* gc = (const float4*)Wc;
        float4* sc = (float4*)&Wcs[0][0];
#pragma unroll
        for (int q = 0; q < 16; ++q) sc[t + q * 256] = gc[t + q * 256];
    }
    const float bcv = bc[lane];
    float tv = temp[0];
    tv = fminf(fmaxf(tv, 0.5f), 5.0f);
    __syncthreads();

    for (int r = 0; r < 2; ++r) {
        const int tk0 = t0 + w * 8 + r * 4;
#pragma unroll
        for (int c = 0; c < 4; ++c)
#pragma unroll
            for (int p = 0; p < 4; ++p)
                hlb[w][c][p * 64 + lane] =
                    hl[(size_t)(tk0 + c) * PROJ + p * 64 + lane];
        __syncthreads();

        float acc[4] = { bcv, bcv, bcv, bcv };
#pragma unroll
        for (int j4 = 0; j4 < PROJ; j4 += 4) {
            const float4 hb0 = *(const float4*)&hlb[w][0][j4];
            const float4 hb1 = *(const float4*)&hlb[w][1][j4];
            const float4 hb2 = *(const float4*)&hlb[w][2][j4];
            const float4 hb3 = *(const float4*)&hlb[w][3][j4];
#pragma unroll
            for (int dd = 0; dd < 4; ++dd) {
                const float wv = Wcs[j4 + dd][lane];
                acc[0] = fmaf(((const float*)&hb0)[dd], wv, acc[0]);
                acc[1] = fmaf(((const float*)&hb1)[dd], wv, acc[1]);
                acc[2] = fmaf(((const float*)&hb2)[dd], wv, acc[2]);
                acc[3] = fmaf(((const float*)&hb3)[dd], wv, acc[3]);
            }
        }

#pragma unroll
        for (int c = 0; c < 4; ++c) {
            const int tk = tk0 + c;
            const float gl = acc[c] / tv;

            // top-1 (ties -> lowest index, matching jax.lax.top_k)
            float v1 = gl; int i1 = lane;
#pragma unroll
            for (int off = 32; off >= 1; off >>= 1) {
                const float ov = __shfl_xor(v1, off);
                const int   oi = __shfl_xor(i1, off);
                if (ov > v1 || (ov == v1 && oi < i1)) { v1 = ov; i1 = oi; }
            }
            // top-2: mask out winner
            float v2 = (lane == i1) ? -INFINITY : gl; int i2 = lane;
#pragma unroll
            for (int off = 32; off >= 1; off >>= 1) {
                const float ov = __shfl_xor(v2, off);
                const int   oi = __shfl_xor(i2, off);
                if (ov > v2 || (ov == v2 && oi < i2)) { v2 = ov; i2 = oi; }
            }

            const float e2 = expf(v2 - v1);       // softmax over [v1, v2]
            const float s  = 1.f + e2;
            const float g1 = 1.f / s;
            const float g2 = e2 / s;

            out[GATES_OFF + (size_t)tk * NE + lane] =
                (lane == i1) ? g1 : ((lane == i2) ? g2 : 0.f);
            if (lane == 0) out[IDX_OFF + (size_t)tk * 2 + 0] = (float)i1;
            if (lane == 1) out[IDX_OFF + (size_t)tk * 2 + 1] = (float)i2;
            out[GL_OFF + (size_t)tk * NE + lane] = gl;
        }
        __syncthreads();   // protect hlb before next round
    }
}

// ---------------------------------------------------------------------------
extern "C" void kernel_launch(void* const* d_in, const int* in_sizes, int n_in,
                              void* d_out, int out_size, void* d_ws, size_t ws_size,
                              hipStream_t stream)
{
    (void)in_sizes; (void)n_in; (void)out_size; (void)ws_size;

    const float* x    = (const float*)d_in[0];
    const float* Wp   = (const float*)d_in[1];
    const float* bp   = (const float*)d_in[2];
    const float* W1   = (const float*)d_in[3];
    const float* b1   = (const float*)d_in[4];
    const float* W2   = (const float*)d_in[5];
    const float* b2   = (const float*)d_in[6];
    const float* Wc   = (const float*)d_in[7];
    const float* bc   = (const float*)d_in[8];
    const float* temp = (const float*)d_in[9];
    // d_in[10] = noise_scale (unused in eval mode)

    float* out = (float*)d_out;
    float* h   = (float*)d_ws;                        // 16384*256 f32 = 16.8 MB
    float* hl  = h + (size_t)NT * PROJ;               // 16384*256 f32 = 16.8 MB

    k1_gemm <<<dim3(NT / K1_BM, PROJ / K1_BN), 256, 0, stream>>>(x, Wp, bp, h);
    k2_heads<<<dim3(NT / 64, NH),              256, 0, stream>>>(h, W1, b1, W2, b2, hl);
    k3_gate <<<dim3(NT / 32),                  256, 0, stream>>>(hl, Wc, bc, temp, out);
}

// Round 2
// 393.794 us; speedup vs baseline: 1.7719x; 1.7719x over previous
//
#include <hip/hip_runtime.h>
#include <math.h>

#define NT   16384
#define KD   2048
#define PROJ 256
#define NH   4
#define HD   64
#define NE   64

#define GATES_OFF 0
#define IDX_OFF   (NT * NE)            // 1048576
#define GL_OFF    (NT * NE + NT * 2)   // 1081344

// ---------------------------------------------------------------------------
// K1: h_T[c][tok] = sum_k x[tok][k] * Wp[k][c] + bp[c]   (output TRANSPOSED)
// Tile 64m(tok) x 64n(c), BK=16, 256 thr, per-thread 4m x 4n outer product.
// grid (256,4) = 1024 blocks -> 4 blocks/CU -> 16 waves/CU.
// Double-buffered LDS, ONE __syncthreads per k-tile, register prefetch.
// Epilogue transposes the C-tile through LDS for coalesced h_T stores.
// ---------------------------------------------------------------------------
__global__ __launch_bounds__(256) void k1_gemm(const float* __restrict__ x,
                                               const float* __restrict__ Wp,
                                               const float* __restrict__ bp,
                                               float* __restrict__ hT)
{
    __shared__ float As[2][16][68];   // k-major A, pad 68: staging writes 2-way only
    __shared__ float Bs[2][16][64];
    __shared__ float Ts[64][68];      // epilogue transpose buffer [n][m]

    const int t  = threadIdx.x;
    const int ng = t & 15;            // n-group: c = n0 + ng*4 + j
    const int mg = t >> 4;            // m-group: tok = m0 + mg*4 + i
    const int m0 = blockIdx.x * 64;
    const int n0 = blockIdx.y * 64;

    // staging decomposition
    const int ami = t >> 2;           // A row (m) 0..63
    const int akq = (t & 3) * 4;      // A k sub-offset {0,4,8,12}
    const int bkr = t >> 4;           // B row (k) 0..15
    const int bnq = (t & 15) * 4;     // B n sub-offset

    const float* xa = &x[(size_t)(m0 + ami) * KD + akq];
    const float* wb = &Wp[(size_t)bkr * PROJ + n0 + bnq];

    float4 pa = *(const float4*)xa;
    float4 pb = *(const float4*)wb;

    float acc[4][4], accT[4][4];
#pragma unroll
    for (int i = 0; i < 4; ++i)
#pragma unroll
        for (int j = 0; j < 4; ++j) { acc[i][j] = 0.f; accT[i][j] = 0.f; }

    const int NTILE = KD / 16;        // 128
    for (int ti = 0; ti < NTILE; ++ti) {
        const int buf = ti & 1;
        As[buf][akq + 0][ami] = pa.x;
        As[buf][akq + 1][ami] = pa.y;
        As[buf][akq + 2][ami] = pa.z;
        As[buf][akq + 3][ami] = pa.w;
        *(float4*)&Bs[buf][bkr][bnq] = pb;
        __syncthreads();              // write(buf) visible; everyone done reading buf
        if (ti + 1 < NTILE) {         // prefetch next tile (overlaps compute)
            pa = *(const float4*)(xa + (ti + 1) * 16);
            pb = *(const float4*)(wb + (size_t)(ti + 1) * 16 * PROJ);
        }
#pragma unroll
        for (int kk = 0; kk < 16; ++kk) {
            const float4 a = *(const float4*)&As[buf][kk][mg * 4];
            const float4 b = *(const float4*)&Bs[buf][kk][ng * 4];
            const float av[4] = { a.x, a.y, a.z, a.w };
            const float bv[4] = { b.x, b.y, b.z, b.w };
#pragma unroll
            for (int i = 0; i < 4; ++i)
#pragma unroll
                for (int j = 0; j < 4; ++j)
                    acc[i][j] = fmaf(av[i], bv[j], acc[i][j]);
        }
        if ((ti & 31) == 31) {        // fold every 512 k: bounds rounding noise
#pragma unroll
            for (int i = 0; i < 4; ++i)
#pragma unroll
                for (int j = 0; j < 4; ++j) { accT[i][j] += acc[i][j]; acc[i][j] = 0.f; }
        }
    }

    // epilogue: bias, transpose through LDS, coalesced channel-major store
    const float4 bpv = *(const float4*)&bp[n0 + ng * 4];
    const float bb[4] = { bpv.x, bpv.y, bpv.z, bpv.w };
#pragma unroll
    for (int j = 0; j < 4; ++j) {
        float4 v;
        v.x = accT[0][j] + bb[j];
        v.y = accT[1][j] + bb[j];
        v.z = accT[2][j] + bb[j];
        v.w = accT[3][j] + bb[j];
        *(float4*)&Ts[ng * 4 + j][mg * 4] = v;
    }
    __syncthreads();
    {
        const int r = t >> 2;         // n row 0..63
        const int c = t & 3;          // m chunk
        float* dst = &hT[(size_t)(n0 + r) * NT + m0];
#pragma unroll
        for (int q = 0; q < 4; ++q)
            *(float4*)&dst[c * 4 + q * 16] = *(const float4*)&Ts[r][c * 4 + q * 16];
    }
}

// ---------------------------------------------------------------------------
// K2: per head: hid = relu(h @ W1 + b1); hl = hid @ W2 + b2  (both 64x64 GEMMs)
// Consumes/produces channel-major h_T / hl_T. Block: 256 thr, 128 tokens,
// one head. Per-thread 4e x 8tok register tile; W1/W2 staged in LDS; hid tile
// through padded LDS. B-fragments are coalesced float4 GLOBAL loads (L2-hot).
// ---------------------------------------------------------------------------
__global__ __launch_bounds__(256) void k2_heads(const float* __restrict__ hT,
                                                const float* __restrict__ W1,
                                                const float* __restrict__ b1,
                                                const float* __restrict__ W2,
                                                const float* __restrict__ b2,
                                                float* __restrict__ hlT)
{
    __shared__ float W1s[64][64];
    __shared__ float W2s[64][64];
    __shared__ float Hs[64][132];     // hid tile [d2][tok], pad 132

    const int t    = threadIdx.x;
    const int eg   = t & 15;          // e-group: e = eg*4 + j
    const int tg   = t >> 4;          // tok-group: tok = tok0 + tg*8 + i
    const int head = blockIdx.y;
    const int tok0 = blockIdx.x * 128;

    {   // stage weights (coalesced float4)
        const float4* g1 = (const float4*)(W1 + (size_t)head * HD * HD);
        const float4* g2 = (const float4*)(W2 + (size_t)head * HD * HD);
        float4* s1 = (float4*)&W1s[0][0];
        float4* s2 = (float4*)&W2s[0][0];
#pragma unroll
        for (int q = 0; q < 4; ++q) {
            s1[t + q * 256] = g1[t + q * 256];
            s2[t + q * 256] = g2[t + q * 256];
        }
    }
    const float4 b1v = *(const float4*)&b1[head * HD + eg * 4];
    const float4 b2v = *(const float4*)&b2[head * HD + eg * 4];
    __syncthreads();

    // ---- stage 1: hid[e][tok] = relu(b1 + sum_d h_T[head*64+d][tok]*W1[d][e])
    float acc[4][8];
    {
        const float bb[4] = { b1v.x, b1v.y, b1v.z, b1v.w };
#pragma unroll
        for (int j = 0; j < 4; ++j)
#pragma unroll
            for (int i = 0; i < 8; ++i) acc[j][i] = bb[j];
    }
    const float* hbase = &hT[(size_t)(head * HD) * NT + tok0 + tg * 8];
#pragma unroll 4
    for (int d = 0; d < HD; ++d) {
        const float4 w  = *(const float4*)&W1s[d][eg * 4];
        const float4 h0 = *(const float4*)&hbase[(size_t)d * NT];
        const float4 h1 = *(const float4*)&hbase[(size_t)d * NT + 4];
        const float wv[4] = { w.x, w.y, w.z, w.w };
        const float hv[8] = { h0.x, h0.y, h0.z, h0.w, h1.x, h1.y, h1.z, h1.w };
#pragma unroll
        for (int j = 0; j < 4; ++j)
#pragma unroll
            for (int i = 0; i < 8; ++i)
                acc[j][i] = fmaf(wv[j], hv[i], acc[j][i]);
    }
#pragma unroll
    for (int j = 0; j < 4; ++j) {
        float4 lo, hi;
        lo.x = fmaxf(acc[j][0], 0.f); lo.y = fmaxf(acc[j][1], 0.f);
        lo.z = fmaxf(acc[j][2], 0.f); lo.w = fmaxf(acc[j][3], 0.f);
        hi.x = fmaxf(acc[j][4], 0.f); hi.y = fmaxf(acc[j][5], 0.f);
        hi.z = fmaxf(acc[j][6], 0.f); hi.w = fmaxf(acc[j][7], 0.f);
        *(float4*)&Hs[eg * 4 + j][tg * 8]     = lo;
        *(float4*)&Hs[eg * 4 + j][tg * 8 + 4] = hi;
    }
    __syncthreads();

    // ---- stage 2: hl[e][tok] = b2 + sum_d2 Hs[d2][tok]*W2[d2][e]
    {
        const float bb[4] = { b2v.x, b2v.y, b2v.z, b2v.w };
#pragma unroll
        for (int j = 0; j < 4; ++j)
#pragma unroll
            for (int i = 0; i < 8; ++i) acc[j][i] = bb[j];
    }
#pragma unroll 4
    for (int d = 0; d < HD; ++d) {
        const float4 w  = *(const float4*)&W2s[d][eg * 4];
        const float4 h0 = *(const float4*)&Hs[d][tg * 8];
        const float4 h1 = *(const float4*)&Hs[d][tg * 8 + 4];
        const float wv[4] = { w.x, w.y, w.z, w.w };
        const float hv[8] = { h0.x, h0.y, h0.z, h0.w, h1.x, h1.y, h1.z, h1.w };
#pragma unroll
        for (int j = 0; j < 4; ++j)
#pragma unroll
            for (int i = 0; i < 8; ++i)
                acc[j][i] = fmaf(wv[j], hv[i], acc[j][i]);
    }
#pragma unroll
    for (int j = 0; j < 4; ++j) {
        float4 lo = { acc[j][0], acc[j][1], acc[j][2], acc[j][3] };
        float4 hi = { acc[j][4], acc[j][5], acc[j][6], acc[j][7] };
        float* dst = &hlT[(size_t)(head * HD + eg * 4 + j) * NT + tok0 + tg * 8];
        *(float4*)&dst[0] = lo;
        *(float4*)&dst[4] = hi;
    }
}

// ---------------------------------------------------------------------------
// K3: gl[tok][e] = (hl_T[:, tok] . Wc[:, e] + bc[e]) / clip(T); top-2 softmax.
// 512 thr, 64 tokens/block, per-thread 4e x 2tok. No LDS: Wc (64 KB) and
// hl_T tile are L1/L2-resident. Top-2 via 4-step shfl_xor over 16 eg-lanes.
// ---------------------------------------------------------------------------
__global__ __launch_bounds__(512) void k3_gate(const float* __restrict__ hlT,
                                               const float* __restrict__ Wc,
                                               const float* __restrict__ bc,
                                               const float* __restrict__ temp,
                                               float* __restrict__ out)
{
    const int t    = threadIdx.x;
    const int eg   = t & 15;          // e = eg*4 + j  (low lane bits -> shfl ok)
    const int tg   = t >> 4;          // 0..31: tok = tok0 + tg*2 + i
    const int tok0 = blockIdx.x * 64;

    const float tv  = fminf(fmaxf(temp[0], 0.5f), 5.0f);
    const float inv = 1.0f / tv;      // uniform scale: ordering identical to /tv
    const float4 bcv = *(const float4*)&bc[eg * 4];

    float acc[4][2];
    acc[0][0] = bcv.x; acc[0][1] = bcv.x;
    acc[1][0] = bcv.y; acc[1][1] = bcv.y;
    acc[2][0] = bcv.z; acc[2][1] = bcv.z;
    acc[3][0] = bcv.w; acc[3][1] = bcv.w;

    const float* hb = &hlT[tok0 + tg * 2];
#pragma unroll 8
    for (int k = 0; k < PROJ; ++k) {
        const float2 hv = *(const float2*)&hb[(size_t)k * NT];
        const float4 wv = *(const float4*)&Wc[k * NE + eg * 4];
        const float wa[4] = { wv.x, wv.y, wv.z, wv.w };
#pragma unroll
        for (int j = 0; j < 4; ++j) {
            acc[j][0] = fmaf(wa[j], hv.x, acc[j][0]);
            acc[j][1] = fmaf(wa[j], hv.y, acc[j][1]);
        }
    }

#pragma unroll
    for (int i = 0; i < 2; ++i) {
        const int tok = tok0 + tg * 2 + i;
        float gl_[4];
#pragma unroll
        for (int j = 0; j < 4; ++j) gl_[j] = acc[j][i] * inv;

        // top-1 (strict > keeps lowest index; cross-lane ties -> lower index)
        float v1 = gl_[0]; int i1 = eg * 4;
#pragma unroll
        for (int j = 1; j < 4; ++j)
            if (gl_[j] > v1) { v1 = gl_[j]; i1 = eg * 4 + j; }
#pragma unroll
        for (int off = 8; off >= 1; off >>= 1) {
            const float ov = __shfl_xor(v1, off);
            const int   oi = __shfl_xor(i1, off);
            if (ov > v1 || (ov == v1 && oi < i1)) { v1 = ov; i1 = oi; }
        }
        // top-2: exclude winner
        float v2 = -INFINITY; int i2 = NE;
#pragma unroll
        for (int j = 0; j < 4; ++j) {
            const int e = eg * 4 + j;
            if (e != i1 && gl_[j] > v2) { v2 = gl_[j]; i2 = e; }
        }
#pragma unroll
        for (int off = 8; off >= 1; off >>= 1) {
            const float ov = __shfl_xor(v2, off);
            const int   oi = __shfl_xor(i2, off);
            if (ov > v2 || (ov == v2 && oi < i2)) { v2 = ov; i2 = oi; }
        }

        const float e2  = expf(v2 - v1);
        const float s   = 1.f + e2;
        const float g1v = 1.f / s;
        const float g2v = e2 / s;

        float4 gv;
        {
            const int e0 = eg * 4;
            gv.x = (e0 + 0 == i1) ? g1v : ((e0 + 0 == i2) ? g2v : 0.f);
            gv.y = (e0 + 1 == i1) ? g1v : ((e0 + 1 == i2) ? g2v : 0.f);
            gv.z = (e0 + 2 == i1) ? g1v : ((e0 + 2 == i2) ? g2v : 0.f);
            gv.w = (e0 + 3 == i1) ? g1v : ((e0 + 3 == i2) ? g2v : 0.f);
        }
        *(float4*)&out[GATES_OFF + (size_t)tok * NE + eg * 4] = gv;
        const float4 glv = { gl_[0], gl_[1], gl_[2], gl_[3] };
        *(float4*)&out[GL_OFF + (size_t)tok * NE + eg * 4] = glv;
        if (eg == 0) {
            out[IDX_OFF + (size_t)tok * 2 + 0] = (float)i1;
            out[IDX_OFF + (size_t)tok * 2 + 1] = (float)i2;
        }
    }
}

// ---------------------------------------------------------------------------
extern "C" void kernel_launch(void* const* d_in, const int* in_sizes, int n_in,
                              void* d_out, int out_size, void* d_ws, size_t ws_size,
                              hipStream_t stream)
{
    (void)in_sizes; (void)n_in; (void)out_size; (void)ws_size;

    const float* x    = (const float*)d_in[0];
    const float* Wp   = (const float*)d_in[1];
    const float* bp   = (const float*)d_in[2];
    const float* W1   = (const float*)d_in[3];
    const float* b1   = (const float*)d_in[4];
    const float* W2   = (const float*)d_in[5];
    const float* b2   = (const float*)d_in[6];
    const float* Wc   = (const float*)d_in[7];
    const float* bc   = (const float*)d_in[8];
    const float* temp = (const float*)d_in[9];

    float* out = (float*)d_out;
    float* hT  = (float*)d_ws;                        // [256][16384] f32, 16.8 MB
    float* hlT = hT + (size_t)PROJ * NT;              // [256][16384] f32, 16.8 MB

    k1_gemm <<<dim3(NT / 64, PROJ / 64), 256, 0, stream>>>(x, Wp, bp, hT);
    k2_heads<<<dim3(NT / 128, NH),       256, 0, stream>>>(hT, W1, b1, W2, b2, hlT);
    k3_gate <<<dim3(NT / 64),            512, 0, stream>>>(hlT, Wc, bc, temp, out);
}

// Round 3
// 320.995 us; speedup vs baseline: 2.1737x; 1.2268x over previous
//
#include <hip/hip_runtime.h>
#include <math.h>

#define NT   16384
#define KD   2048
#define PROJ 256
#define NH   4
#define HD   64
#define NE   64

#define GATES_OFF 0
#define IDX_OFF   (NT * NE)            // 1048576
#define GL_OFF    (NT * NE + NT * 2)   // 1081344

// ---------------------------------------------------------------------------
// K1: h_T[c][tok] = sum_k x[tok][k] * Wp[k][c] + bp[c]   (channel-major out)
// Tile 128m x 64n, BK=32, 256 thr; per-thread 8m x 4n outer product
// (32 FMA per 3 ds_read_b128 -> VALU-dominant). Grid (128,4)=512 blocks.
// Double-buffered LDS, ONE barrier per k-tile, register prefetch of the
// next tile's global data. Fold accumulators every 512 k for low noise.
// ---------------------------------------------------------------------------
#define K1_BM 128
#define K1_BN 64
#define K1_BK 32

__global__ __launch_bounds__(256) void k1_gemm(const float* __restrict__ x,
                                               const float* __restrict__ Wp,
                                               const float* __restrict__ bp,
                                               float* __restrict__ hT)
{
    __shared__ float As[2][K1_BK][132];   // k-major A, pad->conflict-free
    __shared__ float Bs[2][K1_BK][64];

    const int t  = threadIdx.x;
    const int ng = t & 15;            // n: c = n0 + ng*4 + j
    const int mg = t >> 4;            // m: tok = m0 + mg*8 + i
    const int m0 = blockIdx.x * K1_BM;
    const int n0 = blockIdx.y * K1_BN;

    // staging decomposition
    const int ar  = t >> 1;           // A row (m) 0..127
    const int akq = (t & 1) * 16;     // A k half {0,16}
    const int bkr = t >> 3;           // B row (k) 0..31
    const int bnq = (t & 7) * 8;      // B n offset {0,8,...,56}

    const float* xa = &x[(size_t)(m0 + ar) * KD + akq];
    const float* wb = &Wp[(size_t)bkr * PROJ + n0 + bnq];

    float4 pa0 = *(const float4*)(xa + 0);
    float4 pa1 = *(const float4*)(xa + 4);
    float4 pa2 = *(const float4*)(xa + 8);
    float4 pa3 = *(const float4*)(xa + 12);
    float4 pb0 = *(const float4*)(wb + 0);
    float4 pb1 = *(const float4*)(wb + 4);

    float acc[8][4], accT[8][4];
#pragma unroll
    for (int i = 0; i < 8; ++i)
#pragma unroll
        for (int j = 0; j < 4; ++j) { acc[i][j] = 0.f; accT[i][j] = 0.f; }

    const int NTILE = KD / K1_BK;     // 64
    for (int ti = 0; ti < NTILE; ++ti) {
        const int buf = ti & 1;
        // ---- stage current tile (regs -> LDS)
        As[buf][akq +  0][ar] = pa0.x; As[buf][akq +  1][ar] = pa0.y;
        As[buf][akq +  2][ar] = pa0.z; As[buf][akq +  3][ar] = pa0.w;
        As[buf][akq +  4][ar] = pa1.x; As[buf][akq +  5][ar] = pa1.y;
        As[buf][akq +  6][ar] = pa1.z; As[buf][akq +  7][ar] = pa1.w;
        As[buf][akq +  8][ar] = pa2.x; As[buf][akq +  9][ar] = pa2.y;
        As[buf][akq + 10][ar] = pa2.z; As[buf][akq + 11][ar] = pa2.w;
        As[buf][akq + 12][ar] = pa3.x; As[buf][akq + 13][ar] = pa3.y;
        As[buf][akq + 14][ar] = pa3.z; As[buf][akq + 15][ar] = pa3.w;
        *(float4*)&Bs[buf][bkr][bnq]     = pb0;
        *(float4*)&Bs[buf][bkr][bnq + 4] = pb1;
        __syncthreads();              // writes(buf) visible; buf^1 free for next writes
        // ---- prefetch next tile's global data (overlaps compute below)
        if (ti + 1 < NTILE) {
            const float* xn = xa + (ti + 1) * K1_BK;
            const float* wn = wb + (size_t)(ti + 1) * K1_BK * PROJ;
            pa0 = *(const float4*)(xn + 0);
            pa1 = *(const float4*)(xn + 4);
            pa2 = *(const float4*)(xn + 8);
            pa3 = *(const float4*)(xn + 12);
            pb0 = *(const float4*)(wn + 0);
            pb1 = *(const float4*)(wn + 4);
        }
        // ---- compute
#pragma unroll
        for (int kk = 0; kk < K1_BK; ++kk) {
            const float4 a0 = *(const float4*)&As[buf][kk][mg * 8];
            const float4 a1 = *(const float4*)&As[buf][kk][mg * 8 + 4];
            const float4 b  = *(const float4*)&Bs[buf][kk][ng * 4];
            const float av[8] = { a0.x, a0.y, a0.z, a0.w, a1.x, a1.y, a1.z, a1.w };
            const float bv[4] = { b.x, b.y, b.z, b.w };
#pragma unroll
            for (int i = 0; i < 8; ++i)
#pragma unroll
                for (int j = 0; j < 4; ++j)
                    acc[i][j] = fmaf(av[i], bv[j], acc[i][j]);
        }
        if ((ti & 15) == 15) {        // fold every 512 k: bounds rounding noise
#pragma unroll
            for (int i = 0; i < 8; ++i)
#pragma unroll
                for (int j = 0; j < 4; ++j) { accT[i][j] += acc[i][j]; acc[i][j] = 0.f; }
        }
    }

    // ---- epilogue: bias + direct channel-major stores (2 x float4 per col)
    const float4 bpv = *(const float4*)&bp[n0 + ng * 4];
    const float bb[4] = { bpv.x, bpv.y, bpv.z, bpv.w };
#pragma unroll
    for (int j = 0; j < 4; ++j) {
        float4 lo, hi;
        lo.x = accT[0][j] + bb[j]; lo.y = accT[1][j] + bb[j];
        lo.z = accT[2][j] + bb[j]; lo.w = accT[3][j] + bb[j];
        hi.x = accT[4][j] + bb[j]; hi.y = accT[5][j] + bb[j];
        hi.z = accT[6][j] + bb[j]; hi.w = accT[7][j] + bb[j];
        float* dst = &hT[(size_t)(n0 + ng * 4 + j) * NT + m0 + mg * 8];
        *(float4*)&dst[0] = lo;
        *(float4*)&dst[4] = hi;
    }
}

// ---------------------------------------------------------------------------
// K2: per head: hid = relu(h @ W1 + b1); hl = hid @ W2 + b2  (both 64x64 GEMMs)
// Consumes/produces channel-major h_T / hl_T. Block: 256 thr, 128 tokens,
// one head. Per-thread 4e x 8tok register tile; W1/W2 staged in LDS; hid tile
// through padded LDS. B-fragments are coalesced float4 GLOBAL loads (L2-hot).
// ---------------------------------------------------------------------------
__global__ __launch_bounds__(256) void k2_heads(const float* __restrict__ hT,
                                                const float* __restrict__ W1,
                                                const float* __restrict__ b1,
                                                const float* __restrict__ W2,
                                                const float* __restrict__ b2,
                                                float* __restrict__ hlT)
{
    __shared__ float W1s[64][64];
    __shared__ float W2s[64][64];
    __shared__ float Hs[64][132];     // hid tile [d2][tok], pad 132

    const int t    = threadIdx.x;
    const int eg   = t & 15;          // e-group: e = eg*4 + j
    const int tg   = t >> 4;          // tok-group: tok = tok0 + tg*8 + i
    const int head = blockIdx.y;
    const int tok0 = blockIdx.x * 128;

    {   // stage weights (coalesced float4)
        const float4* g1 = (const float4*)(W1 + (size_t)head * HD * HD);
        const float4* g2 = (const float4*)(W2 + (size_t)head * HD * HD);
        float4* s1 = (float4*)&W1s[0][0];
        float4* s2 = (float4*)&W2s[0][0];
#pragma unroll
        for (int q = 0; q < 4; ++q) {
            s1[t + q * 256] = g1[t + q * 256];
            s2[t + q * 256] = g2[t + q * 256];
        }
    }
    const float4 b1v = *(const float4*)&b1[head * HD + eg * 4];
    const float4 b2v = *(const float4*)&b2[head * HD + eg * 4];
    __syncthreads();

    // ---- stage 1: hid[e][tok] = relu(b1 + sum_d h_T[head*64+d][tok]*W1[d][e])
    float acc[4][8];
    {
        const float bb[4] = { b1v.x, b1v.y, b1v.z, b1v.w };
#pragma unroll
        for (int j = 0; j < 4; ++j)
#pragma unroll
            for (int i = 0; i < 8; ++i) acc[j][i] = bb[j];
    }
    const float* hbase = &hT[(size_t)(head * HD) * NT + tok0 + tg * 8];
#pragma unroll 4
    for (int d = 0; d < HD; ++d) {
        const float4 w  = *(const float4*)&W1s[d][eg * 4];
        const float4 h0 = *(const float4*)&hbase[(size_t)d * NT];
        const float4 h1 = *(const float4*)&hbase[(size_t)d * NT + 4];
        const float wv[4] = { w.x, w.y, w.z, w.w };
        const float hv[8] = { h0.x, h0.y, h0.z, h0.w, h1.x, h1.y, h1.z, h1.w };
#pragma unroll
        for (int j = 0; j < 4; ++j)
#pragma unroll
            for (int i = 0; i < 8; ++i)
                acc[j][i] = fmaf(wv[j], hv[i], acc[j][i]);
    }
#pragma unroll
    for (int j = 0; j < 4; ++j) {
        float4 lo, hi;
        lo.x = fmaxf(acc[j][0], 0.f); lo.y = fmaxf(acc[j][1], 0.f);
        lo.z = fmaxf(acc[j][2], 0.f); lo.w = fmaxf(acc[j][3], 0.f);
        hi.x = fmaxf(acc[j][4], 0.f); hi.y = fmaxf(acc[j][5], 0.f);
        hi.z = fmaxf(acc[j][6], 0.f); hi.w = fmaxf(acc[j][7], 0.f);
        *(float4*)&Hs[eg * 4 + j][tg * 8]     = lo;
        *(float4*)&Hs[eg * 4 + j][tg * 8 + 4] = hi;
    }
    __syncthreads();

    // ---- stage 2: hl[e][tok] = b2 + sum_d2 Hs[d2][tok]*W2[d2][e]
    {
        const float bb[4] = { b2v.x, b2v.y, b2v.z, b2v.w };
#pragma unroll
        for (int j = 0; j < 4; ++j)
#pragma unroll
            for (int i = 0; i < 8; ++i) acc[j][i] = bb[j];
    }
#pragma unroll 4
    for (int d = 0; d < HD; ++d) {
        const float4 w  = *(const float4*)&W2s[d][eg * 4];
        const float4 h0 = *(const float4*)&Hs[d][tg * 8];
        const float4 h1 = *(const float4*)&Hs[d][tg * 8 + 4];
        const float wv[4] = { w.x, w.y, w.z, w.w };
        const float hv[8] = { h0.x, h0.y, h0.z, h0.w, h1.x, h1.y, h1.z, h1.w };
#pragma unroll
        for (int j = 0; j < 4; ++j)
#pragma unroll
            for (int i = 0; i < 8; ++i)
                acc[j][i] = fmaf(wv[j], hv[i], acc[j][i]);
    }
#pragma unroll
    for (int j = 0; j < 4; ++j) {
        float4 lo = { acc[j][0], acc[j][1], acc[j][2], acc[j][3] };
        float4 hi = { acc[j][4], acc[j][5], acc[j][6], acc[j][7] };
        float* dst = &hlT[(size_t)(head * HD + eg * 4 + j) * NT + tok0 + tg * 8];
        *(float4*)&dst[0] = lo;
        *(float4*)&dst[4] = hi;
    }
}

// ---------------------------------------------------------------------------
// K3: gl[tok][e] = (hl_T[:, tok] . Wc[:, e] + bc[e]) / clip(T); top-2 softmax.
// 512 thr, 64 tokens/block, per-thread 4e x 2tok. No LDS: Wc (64 KB) and
// hl_T tile are L1/L2-resident. Top-2 via 4-step shfl_xor over 16 eg-lanes.
// ---------------------------------------------------------------------------
__global__ __launch_bounds__(512) void k3_gate(const float* __restrict__ hlT,
                                               const float* __restrict__ Wc,
                                               const float* __restrict__ bc,
                                               const float* __restrict__ temp,
                                               float* __restrict__ out)
{
    const int t    = threadIdx.x;
    const int eg   = t & 15;          // e = eg*4 + j  (low lane bits -> shfl ok)
    const int tg   = t >> 4;          // 0..31: tok = tok0 + tg*2 + i
    const int tok0 = blockIdx.x * 64;

    const float tv  = fminf(fmaxf(temp[0], 0.5f), 5.0f);
    const float inv = 1.0f / tv;      // uniform scale: ordering identical to /tv
    const float4 bcv = *(const float4*)&bc[eg * 4];

    float acc[4][2];
    acc[0][0] = bcv.x; acc[0][1] = bcv.x;
    acc[1][0] = bcv.y; acc[1][1] = bcv.y;
    acc[2][0] = bcv.z; acc[2][1] = bcv.z;
    acc[3][0] = bcv.w; acc[3][1] = bcv.w;

    const float* hb = &hlT[tok0 + tg * 2];
#pragma unroll 8
    for (int k = 0; k < PROJ; ++k) {
        const float2 hv = *(const float2*)&hb[(size_t)k * NT];
        const float4 wv = *(const float4*)&Wc[k * NE + eg * 4];
        const float wa[4] = { wv.x, wv.y, wv.z, wv.w };
#pragma unroll
        for (int j = 0; j < 4; ++j) {
            acc[j][0] = fmaf(wa[j], hv.x, acc[j][0]);
            acc[j][1] = fmaf(wa[j], hv.y, acc[j][1]);
        }
    }

#pragma unroll
    for (int i = 0; i < 2; ++i) {
        const int tok = tok0 + tg * 2 + i;
        float gl_[4];
#pragma unroll
        for (int j = 0; j < 4; ++j) gl_[j] = acc[j][i] * inv;

        // top-1 (strict > keeps lowest index; cross-lane ties -> lower index)
        float v1 = gl_[0]; int i1 = eg * 4;
#pragma unroll
        for (int j = 1; j < 4; ++j)
            if (gl_[j] > v1) { v1 = gl_[j]; i1 = eg * 4 + j; }
#pragma unroll
        for (int off = 8; off >= 1; off >>= 1) {
            const float ov = __shfl_xor(v1, off);
            const int   oi = __shfl_xor(i1, off);
            if (ov > v1 || (ov == v1 && oi < i1)) { v1 = ov; i1 = oi; }
        }
        // top-2: exclude winner
        float v2 = -INFINITY; int i2 = NE;
#pragma unroll
        for (int j = 0; j < 4; ++j) {
            const int e = eg * 4 + j;
            if (e != i1 && gl_[j] > v2) { v2 = gl_[j]; i2 = e; }
        }
#pragma unroll
        for (int off = 8; off >= 1; off >>= 1) {
            const float ov = __shfl_xor(v2, off);
            const int   oi = __shfl_xor(i2, off);
            if (ov > v2 || (ov == v2 && oi < i2)) { v2 = ov; i2 = oi; }
        }

        const float e2  = expf(v2 - v1);
        const float s   = 1.f + e2;
        const float g1v = 1.f / s;
        const float g2v = e2 / s;

        float4 gv;
        {
            const int e0 = eg * 4;
            gv.x = (e0 + 0 == i1) ? g1v : ((e0 + 0 == i2) ? g2v : 0.f);
            gv.y = (e0 + 1 == i1) ? g1v : ((e0 + 1 == i2) ? g2v : 0.f);
            gv.z = (e0 + 2 == i1) ? g1v : ((e0 + 2 == i2) ? g2v : 0.f);
            gv.w = (e0 + 3 == i1) ? g1v : ((e0 + 3 == i2) ? g2v : 0.f);
        }
        *(float4*)&out[GATES_OFF + (size_t)tok * NE + eg * 4] = gv;
        const float4 glv = { gl_[0], gl_[1], gl_[2], gl_[3] };
        *(float4*)&out[GL_OFF + (size_t)tok * NE + eg * 4] = glv;
        if (eg == 0) {
            out[IDX_OFF + (size_t)tok * 2 + 0] = (float)i1;
            out[IDX_OFF + (size_t)tok * 2 + 1] = (float)i2;
        }
    }
}

// ---------------------------------------------------------------------------
extern "C" void kernel_launch(void* const* d_in, const int* in_sizes, int n_in,
                              void* d_out, int out_size, void* d_ws, size_t ws_size,
                              hipStream_t stream)
{
    (void)in_sizes; (void)n_in; (void)out_size; (void)ws_size;

    const float* x    = (const float*)d_in[0];
    const float* Wp   = (const float*)d_in[1];
    const float* bp   = (const float*)d_in[2];
    const float* W1   = (const float*)d_in[3];
    const float* b1   = (const float*)d_in[4];
    const float* W2   = (const float*)d_in[5];
    const float* b2   = (const float*)d_in[6];
    const float* Wc   = (const float*)d_in[7];
    const float* bc   = (const float*)d_in[8];
    const float* temp = (const float*)d_in[9];

    float* out = (float*)d_out;
    float* hT  = (float*)d_ws;                        // [256][16384] f32, 16.8 MB
    float* hlT = hT + (size_t)PROJ * NT;              // [256][16384] f32, 16.8 MB

    k1_gemm <<<dim3(NT / K1_BM, PROJ / K1_BN), 256, 0, stream>>>(x, Wp, bp, hT);
    k2_heads<<<dim3(NT / 128, NH),             256, 0, stream>>>(hT, W1, b1, W2, b2, hlT);
    k3_gate <<<dim3(NT / 64),                  512, 0, stream>>>(hlT, Wc, bc, temp, out);
}